// Round 4
// baseline (67.087 us; speedup 1.0000x reference)
//
#include <hip/hip_runtime.h>
#include <math.h>

#define NB   2
#define NP   4096
#define KNN  32
#define DIMC 128
#define NROWS (NB*NP)          // 8192
#define MTOT  (NB*NP*KNN)      // 262144
#define MASKBLOCKS 512         // 16 points each (4 per wave)
#define EGBLOCKS   512         // 16 rows each
#define MAINBLOCKS (NROWS/16)  // 512

static constexpr float R2 = 0.04f;

// ---------------- kB (fat): {mask-build + extract + speed partials} | {e/g GEMM} ----------------
__global__ __launch_bounds__(256) void kB(const float* __restrict__ xyzp,
                                          const float* __restrict__ feat,
                                          const float* __restrict__ Wm,
                                          int* __restrict__ idx,
                                          double* __restrict__ spart,
                                          float* __restrict__ e,
                                          float* __restrict__ g)
{
    __shared__ float smem[8712];   // mask: xy[8192]|idxrow[512]|swr[8]  /  gemm: sf[2048]|wt[4096]

    if (blockIdx.x < MASKBLOCKS) {
#pragma clang fp contract(off)
        float* xy     = smem;                       // [4096][2]
        int*   idxrow = (int*)(smem + NP*2);        // [16][32]
        float* swr    = smem + NP*2 + 16*KNN;       // [4][2]

        const int t    = threadIdx.x;
        const int w    = t >> 6;
        const int lane = t & 63;
        const int b    = blockIdx.x >> 8;           // 256 blocks per batch
        const int p0   = (blockIdx.x & 255) * 16;
        const float* xb = xyzp + (size_t)b*NP*4;

        for (int q = t; q < NP; q += 256) {
            const float4 v = *(const float4*)(xb + (size_t)q*4);
            xy[q*2 + 0] = v.x;
            xy[q*2 + 1] = v.y;
        }
        __syncthreads();

        const int pl0 = p0 + w*4;
        float xi[4], yi[4];
        #pragma unroll
        for (int p = 0; p < 4; ++p) { xi[p] = xy[(pl0+p)*2]; yi[p] = xy[(pl0+p)*2+1]; }

        unsigned long long wacc[4] = {0ULL,0ULL,0ULL,0ULL};
        for (int c = 0; c < NP/64; ++c) {
            const float2 q = *(const float2*)(xy + (size_t)(c*64 + lane)*2);
            const bool keep = (lane == c);
            #pragma unroll
            for (int p = 0; p < 4; ++p) {
                const float dx = xi[p] - q.x;
                const float dy = yi[p] - q.y;
                const float dx2 = dx*dx;
                const float dy2 = dy*dy;
                const unsigned long long m = __ballot((dx2 + dy2) < R2);
                if (keep) wacc[p] = m;              // lane l keeps word l (j in [64l,64l+64))
            }
        }

        // extraction: 32 smallest hit indices (lane-major = ascending j)
        #pragma unroll
        for (int p = 0; p < 4; ++p) {
            unsigned long long wd = wacc[p];
            const int cnt = __popcll(wd);
            int pre = cnt;
            #pragma unroll
            for (int off = 1; off < 64; off <<= 1) {
                const int tv = __shfl_up(pre, off);
                if (lane >= off) pre += tv;
            }
            const int total = __shfl(pre, 63);
            int slot = pre - cnt;                   // exclusive prefix
            unsigned long long ww = wd;
            while (ww != 0ULL && slot < KNN) {
                const int bpos = __builtin_ctzll(ww);
                idxrow[(w*4 + p)*KNN + slot] = lane*64 + bpos;
                ww &= ww - 1ULL;
                ++slot;
            }
            const int iself = pl0 + p;
            for (int kk = min(total, KNN) + lane; kk < KNN; kk += 64)
                idxrow[(w*4 + p)*KNN + kk] = iself;
        }
        __syncthreads();

        // speed partial sums + global idx store
        float sxa = 0.f, sya = 0.f;
        #pragma unroll
        for (int p = 0; p < 4; ++p) {
            const int pt = b*NP + pl0 + p;
            float sxv = 0.f, syv = 0.f;
            if (lane < KNN) {
                const int j = idxrow[(w*4 + p)*KNN + lane];
                idx[(size_t)pt*KNN + lane] = j;
                const float4 pj = *(const float4*)(xb + (size_t)j*4);
                const float4 pi = *(const float4*)(xyzp + (size_t)pt*4);
                const float dz = pi.z - pj.z;
                const float ts = (dz == 0.f) ? 1e-6f : dz;
                const float rts = __builtin_amdgcn_rcpf(ts);
                sxv = (pi.x - pj.x)*rts*640.f;
                syv = (pi.y - pj.y)*rts*480.f;
            }
            sxa += sxv; sya += syv;
        }
        #pragma unroll
        for (int off = 32; off > 0; off >>= 1) {
            sxa += __shfl_down(sxa, off);
            sya += __shfl_down(sya, off);
        }
        if (lane == 0) { swr[w*2] = sxa; swr[w*2+1] = sya; }
        __syncthreads();
        if (t == 0) {
            const double s0 = ((double)swr[0] + (double)swr[2]) + ((double)swr[4] + (double)swr[6]);
            const double s1 = ((double)swr[1] + (double)swr[3]) + ((double)swr[5] + (double)swr[7]);
            spart[(size_t)blockIdx.x*2 + 0] = s0;
            spart[(size_t)blockIdx.x*2 + 1] = s1;
        }
    } else {
        // ---- e = feat@W0, g = feat@W1 : 16 rows x 256 cols, 4x4 per thread ----
        float* sf = smem;            // [16][128]
        float* wt = smem + 2048;     // [16][256] k-tile of [W0|W1]
        const int t    = threadIdx.x;
        const int w    = t >> 6;
        const int lane = t & 63;
        const int r0   = w * 4;
        const int row0 = (blockIdx.x - MASKBLOCKS) * 16;

        for (int q = t; q < 16*DIMC; q += 256)
            sf[q] = feat[(size_t)row0*DIMC + q];

        float acc[4][4];
        #pragma unroll
        for (int i = 0; i < 4; ++i)
            #pragma unroll
            for (int ci = 0; ci < 4; ++ci) acc[i][ci] = 0.f;

        for (int kb = 0; kb < 8; ++kb) {
            __syncthreads();                       // protect wt (and sf on first iter)
            #pragma unroll
            for (int it = 0; it < 16; ++it) {      // stage W rows kb*16..+15, cols 0..255
                const int cc = t;                  // 0..255
                wt[it*256 + cc] = Wm[(size_t)((cc >> 7)*128 + kb*16 + it)*DIMC + (cc & 127)];
            }
            __syncthreads();
            #pragma unroll
            for (int kks = 0; kks < 4; ++kks) {
                const int kk0 = kks*4;
                float4 sfv[4];
                #pragma unroll
                for (int i = 0; i < 4; ++i)
                    sfv[i] = *(const float4*)&sf[(r0 + i)*DIMC + kb*16 + kk0];
                #pragma unroll
                for (int j = 0; j < 4; ++j) {
                    const float w0 = wt[(kk0+j)*256 + lane];
                    const float w1 = wt[(kk0+j)*256 + lane + 64];
                    const float w2v= wt[(kk0+j)*256 + lane + 128];
                    const float w3 = wt[(kk0+j)*256 + lane + 192];
                    #pragma unroll
                    for (int i = 0; i < 4; ++i) {
                        const float s = (j==0) ? sfv[i].x : (j==1) ? sfv[i].y : (j==2) ? sfv[i].z : sfv[i].w;
                        acc[i][0] = fmaf(s, w0, acc[i][0]);
                        acc[i][1] = fmaf(s, w1, acc[i][1]);
                        acc[i][2] = fmaf(s, w2v, acc[i][2]);
                        acc[i][3] = fmaf(s, w3, acc[i][3]);
                    }
                }
            }
        }
        #pragma unroll
        for (int i = 0; i < 4; ++i) {
            const int row = row0 + r0 + i;
            e[(size_t)row*DIMC + lane]      = acc[i][0];
            e[(size_t)row*DIMC + lane + 64] = acc[i][1];
            g[(size_t)row*DIMC + lane]      = acc[i][2];
            g[(size_t)row*DIMC + lane + 64] = acc[i][3];
        }
    }
}

// ---------------- kD: per-pair h0 (no mean-speed), min/max over K, stat partials ----------------
__global__ __launch_bounds__(256) void kD(const float* __restrict__ xyzp,
                                          const int* __restrict__ idx,
                                          const float* __restrict__ e,
                                          const float* __restrict__ g,
                                          const float* __restrict__ Wm,
                                          const float* __restrict__ bbias,
                                          float* __restrict__ hmaxA,
                                          float* __restrict__ hminA,
                                          float* __restrict__ stpartT)
{
    __shared__ float geo[4][KNN][8];
    __shared__ float l1[4][DIMC], l2[4][DIMC];

    const int t        = threadIdx.x;
    const int w        = t >> 6;
    const int lane     = t & 63;
    const int c0       = lane * 2;
    const int row_base = blockIdx.x * 16;
    const int b        = row_base >> 12;

    float w2a[7], w2b[7];
    #pragma unroll
    for (int r = 0; r < 7; ++r) {
        w2a[r] = Wm[(256 + r)*DIMC + c0];
        w2b[r] = Wm[(256 + r)*DIMC + c0 + 1];
    }
    const float cva = bbias[c0];
    const float cvb = bbias[c0 + 1];

    const float* gb = g + (size_t)b*NP*DIMC + c0;
    float s1a = 0.f, s1b = 0.f, s2a = 0.f, s2b = 0.f;

    for (int rr = 0; rr < 4; ++rr) {
        const int row = row_base + w*4 + rr;
        if (lane < KNN) {
            const int j = idx[(size_t)row*KNN + lane];
            const float4 pj = *(const float4*)(xyzp + ((size_t)b*NP + j)*4);
            const float4 pi = *(const float4*)(xyzp + (size_t)row*4);
            const float dx = pi.x - pj.x;
            const float dy = pi.y - pj.y;
            const float dz = pi.z - pj.z;
            const float dwv = pi.w - pj.w;
            const float ts  = (dz == 0.f) ? 1e-6f : dz;
            const float rts = __builtin_amdgcn_rcpf(ts);
            geo[w][lane][0] = dx;
            geo[w][lane][1] = dy;
            geo[w][lane][2] = dz;
            geo[w][lane][3] = dwv;
            geo[w][lane][4] = dx*rts*640.f;
            geo[w][lane][5] = dy*rts*480.f;
            geo[w][lane][6] = fabsf(dwv);
            geo[w][lane][7] = __int_as_float(j);
        }
        __builtin_amdgcn_wave_barrier();   // geo is wave-private; DS ops are in-order per wave

        const float2 ee = *(const float2*)(e + (size_t)row*DIMC + c0);
        float mxa = -INFINITY, mxb = -INFINITY, mna = INFINITY, mnb = INFINITY;
        #pragma unroll 4
        for (int k = 0; k < KNN; ++k) {
            const float4 g0 = *(const float4*)&geo[w][k][0];
            const float4 g1 = *(const float4*)&geo[w][k][4];
            const int j = __float_as_int(g1.w);
            const float2 gg = *(const float2*)(gb + (size_t)j*DIMC);
            float ha = ee.x + gg.x + cva;
            float hb = ee.y + gg.y + cvb;
            ha = fmaf(g0.x, w2a[0], ha); hb = fmaf(g0.x, w2b[0], hb);
            ha = fmaf(g0.y, w2a[1], ha); hb = fmaf(g0.y, w2b[1], hb);
            ha = fmaf(g0.z, w2a[2], ha); hb = fmaf(g0.z, w2b[2], hb);
            ha = fmaf(g0.w, w2a[3], ha); hb = fmaf(g0.w, w2b[3], hb);
            ha = fmaf(g1.x, w2a[4], ha); hb = fmaf(g1.x, w2b[4], hb);
            ha = fmaf(g1.y, w2a[5], ha); hb = fmaf(g1.y, w2b[5], hb);
            ha = fmaf(g1.z, w2a[6], ha); hb = fmaf(g1.z, w2b[6], hb);
            mxa = fmaxf(mxa, ha); mna = fminf(mna, ha);
            mxb = fmaxf(mxb, hb); mnb = fminf(mnb, hb);
            s1a += ha; s2a = fmaf(ha, ha, s2a);
            s1b += hb; s2b = fmaf(hb, hb, s2b);
        }
        *(float2*)(hmaxA + (size_t)row*DIMC + c0) = make_float2(mxa, mxb);
        *(float2*)(hminA + (size_t)row*DIMC + c0) = make_float2(mna, mnb);
        __builtin_amdgcn_wave_barrier();
    }

    l1[w][c0] = s1a; l1[w][c0+1] = s1b;
    l2[w][c0] = s2a; l2[w][c0+1] = s2b;
    __syncthreads();
    if (t < DIMC) {
        const float v = ((l1[0][t] + l1[1][t]) + l1[2][t]) + l1[3][t];
        stpartT[(size_t)t*MAINBLOCKS + blockIdx.x] = v;
    } else {
        const int tc = t - DIMC;
        const float v = ((l2[0][tc] + l2[1][tc]) + l2[2][tc]) + l2[3][tc];
        stpartT[(size_t)t*MAINBLOCKS + blockIdx.x] = v;
    }
}

// ---------------- kE: stat + mean-speed reduce, per-batch affine coefficients ----------------
__global__ __launch_bounds__(256) void kE(const float* __restrict__ stpartT,
                                          const double* __restrict__ spart,
                                          const float* __restrict__ Wm,
                                          const float* __restrict__ gamma,
                                          const float* __restrict__ beta,
                                          float* __restrict__ abuf,
                                          float* __restrict__ dbuf2)
{
    __shared__ double red[256][8];   // 16 KB
    const int c = blockIdx.x;        // 0..127
    const int t = threadIdx.x;

    red[t][0] = spart[(size_t)t*2];            // sx batch0
    red[t][1] = spart[(size_t)t*2 + 1];        // sy batch0
    red[t][2] = spart[(size_t)(t+256)*2];      // sx batch1
    red[t][3] = spart[(size_t)(t+256)*2 + 1];  // sy batch1
    red[t][4] = (double)stpartT[(size_t)c*MAINBLOCKS + t];                    // S1 b0
    red[t][5] = (double)stpartT[(size_t)c*MAINBLOCKS + 256 + t];              // S1 b1
    red[t][6] = (double)stpartT[(size_t)(c + DIMC)*MAINBLOCKS + t];           // S2 b0
    red[t][7] = (double)stpartT[(size_t)(c + DIMC)*MAINBLOCKS + 256 + t];     // S2 b1
    __syncthreads();
    for (int st = 128; st > 0; st >>= 1) {
        if (t < st) {
            #pragma unroll
            for (int q = 0; q < 8; ++q) red[t][q] += red[t+st][q];
        }
        __syncthreads();
    }
    if (t == 0) {
        const double NKd = (double)(NP*KNN);
        const float ms0x = (float)(red[0][0] / NKd);
        const float ms0y = (float)(red[0][1] / NKd);
        const float ms1x = (float)(red[0][2] / NKd);
        const float ms1y = (float)(red[0][3] / NKd);
        const float wx = Wm[263*DIMC + c];
        const float wy = Wm[264*DIMC + c];
        const double cb0 = (double)fmaf(ms0x, wx, ms0y*wy);
        const double cb1 = (double)fmaf(ms1x, wx, ms1y*wy);
        const double s1b0 = red[0][4], s1b1 = red[0][5];
        const double s2b0 = red[0][6], s2b1 = red[0][7];
        const double M  = (double)MTOT;
        const double S1 = s1b0 + s1b1 + NKd*(cb0 + cb1);
        const double S2 = (s2b0 + 2.0*cb0*s1b0 + NKd*cb0*cb0)
                        + (s2b1 + 2.0*cb1*s1b1 + NKd*cb1*cb1);
        const double mu  = S1 / M;
        const double var = S2 / M - mu*mu;
        const double inv = 1.0 / sqrt(var + 1e-5);
        const double a  = (double)gamma[c] * inv;
        const double db = (double)beta[c] - mu*a;
        abuf[c] = (float)a;
        dbuf2[c]        = (float)(db + cb0*a);
        dbuf2[DIMC + c] = (float)(db + cb1*a);
    }
}

// ---------------- kF: normalize + relu on the pre-reduced K-extremes ----------------
__global__ __launch_bounds__(256) void kF(const float* __restrict__ hmaxA,
                                          const float* __restrict__ hminA,
                                          const float* __restrict__ abuf,
                                          const float* __restrict__ dbuf2,
                                          float* __restrict__ out)
{
    const int gid = blockIdx.x*256 + threadIdx.x;
    const int row = gid >> 6;
    const int c0  = (gid & 63)*2;
    const int b   = row >> 12;
    const size_t off = (size_t)row*DIMC + c0;
    const float2 mx = *(const float2*)(hmaxA + off);
    const float2 mn = *(const float2*)(hminA + off);
    const float a0 = abuf[c0],  a1 = abuf[c0+1];
    const float d0 = dbuf2[b*DIMC + c0], d1 = dbuf2[b*DIMC + c0 + 1];
    const float h0 = (a0 >= 0.f) ? mx.x : mn.x;
    const float h1 = (a1 >= 0.f) ? mx.y : mn.y;
    float2 o;
    o.x = fmaxf(fmaf(h0, a0, d0), 0.0f);
    o.y = fmaxf(fmaf(h1, a1, d1), 0.0f);
    *(float2*)(out + off) = o;
}

extern "C" void kernel_launch(void* const* d_in, const int* in_sizes, int n_in,
                              void* d_out, int out_size, void* d_ws, size_t ws_size,
                              hipStream_t stream)
{
    const float* xyzp  = (const float*)d_in[0];
    const float* feat  = (const float*)d_in[1];
    const float* Wm    = (const float*)d_in[2];
    const float* bbias = (const float*)d_in[3];
    const float* gamma = (const float*)d_in[4];
    const float* beta  = (const float*)d_in[5];

    char* ws = (char*)d_ws;
    const size_t MB = 1u << 20;
    int*    idx     = (int*)   (ws + 0);             // 1 MB
    float*  g       = (float*) (ws + 1*MB);          // 4 MB
    float*  e       = (float*) (ws + 5*MB);          // 4 MB
    float*  hmaxA   = (float*) (ws + 9*MB);          // 4 MB
    float*  hminA   = (float*) (ws + 13*MB);         // 4 MB
    double* spart   = (double*)(ws + 17*MB);         // 8 KB (512 x double2)
    float*  abuf    = (float*) (ws + 17*MB + 65536); // 512 B
    float*  dbuf2   = (float*) (ws + 17*MB + 66560); // 1 KB (2 x 128)
    float*  stpartT = (float*) (ws + 18*MB);         // 512 KB (256 x 512)

    kB <<<MASKBLOCKS + EGBLOCKS, 256, 0, stream>>>(xyzp, feat, Wm, idx, spart, e, g);
    kD <<<MAINBLOCKS, 256, 0, stream>>>(xyzp, idx, e, g, Wm, bbias, hmaxA, hminA, stpartT);
    kE <<<DIMC, 256, 0, stream>>>(stpartT, spart, Wm, gamma, beta, abuf, dbuf2);
    kF <<<(NROWS*64)/256, 256, 0, stream>>>(hmaxA, hminA, abuf, dbuf2, (float*)d_out);
}

// Round 5
// 62.932 us; speedup vs baseline: 1.0660x; 1.0660x over previous
//
#include <hip/hip_runtime.h>
#include <math.h>

#define NB   2
#define NP   4096
#define KNN  32
#define DIMC 128
#define NROWS (NB*NP)          // 8192
#define MTOT  (NB*NP*KNN)      // 262144
#define K2BLOCKS 512           // 16 points each (4 per wave)
#define MAINBLOCKS 512

static constexpr float R2 = 0.04f;

// ---------------- k1: e = feat@W0, g = feat@W1 (pipe-balanced fp32 GEMM) ----------------
// grid 256 (= 1 block/CU): block = 64 rows x 128 cols (one of e/g), thread = 8x4 tile.
// A read directly from global (L1 broadcast, no DS); B staged in LDS (1 b128 / 32 FMA).
__global__ __launch_bounds__(256) void k1(const float* __restrict__ feat,
                                          const float* __restrict__ Wm,
                                          float* __restrict__ e,
                                          float* __restrict__ g)
{
    __shared__ float wt[32*128];          // 16 KB k-chunk of W
    const int t   = threadIdx.x;
    const int rb  = blockIdx.x >> 1;
    const int cb  = blockIdx.x & 1;       // 0 -> e (W rows 0..127), 1 -> g (W rows 128..255)
    const int tr  = t >> 5;               // 0..7
    const int tc  = t & 31;               // 0..31
    const int r0  = rb*64 + tr*8;
    const int c0  = tc*4;
    const float* wsrc = Wm + (size_t)cb*128*DIMC;

    float acc[8][4];
    #pragma unroll
    for (int i = 0; i < 8; ++i) { acc[i][0]=0.f; acc[i][1]=0.f; acc[i][2]=0.f; acc[i][3]=0.f; }

    for (int kc = 0; kc < 4; ++kc) {
        __syncthreads();
        #pragma unroll
        for (int q = 0; q < 16; ++q) {
            const int id = t + q*256;                 // 0..4095
            wt[id] = wsrc[(size_t)(kc*32 + (id >> 7))*DIMC + (id & 127)];
        }
        __syncthreads();
        #pragma unroll
        for (int k4 = 0; k4 < 8; ++k4) {
            float4 ar[8];
            #pragma unroll
            for (int i = 0; i < 8; ++i)
                ar[i] = *(const float4*)(feat + (size_t)(r0+i)*DIMC + kc*32 + k4*4);
            #pragma unroll
            for (int j = 0; j < 4; ++j) {
                const float4 bv = *(const float4*)(wt + (k4*4+j)*128 + c0);
                #pragma unroll
                for (int i = 0; i < 8; ++i) {
                    const float a = (j==0)?ar[i].x:(j==1)?ar[i].y:(j==2)?ar[i].z:ar[i].w;
                    acc[i][0] = fmaf(a, bv.x, acc[i][0]);
                    acc[i][1] = fmaf(a, bv.y, acc[i][1]);
                    acc[i][2] = fmaf(a, bv.z, acc[i][2]);
                    acc[i][3] = fmaf(a, bv.w, acc[i][3]);
                }
            }
        }
    }
    float* dst = cb ? g : e;
    #pragma unroll
    for (int i = 0; i < 8; ++i)
        *(float4*)(dst + (size_t)(r0+i)*DIMC + c0) =
            make_float4(acc[i][0], acc[i][1], acc[i][2], acc[i][3]);
}

// ---------------- k2: mask + extract + geo + h (min/max over K) + stat partials ----------------
// 512 blocks x 256 thr; 16 points/block, 4/wave. No __syncthreads in main body.
// h layout: lane = (half = row-of-pair, lq = channel-quad); 4 channels/lane.
__global__ __launch_bounds__(256) void k2(const float* __restrict__ xyzp,
                                          const float* __restrict__ e,
                                          const float* __restrict__ g,
                                          const float* __restrict__ Wm,
                                          const float* __restrict__ bbias,
                                          double* __restrict__ spart,
                                          float* __restrict__ hmaxA,
                                          float* __restrict__ hminA,
                                          float* __restrict__ stpartT)
{
    __shared__ float xy[NP*2];                 // 32 KB
    __shared__ int   idxrow[16*KNN];           // 2 KB
    __shared__ float geo[4][2][KNN][8];        // 8 KB
    __shared__ float l1s[8][DIMC];             // 4 KB
    __shared__ float l2s[8][DIMC];             // 4 KB
    __shared__ float swr[8];

    const int bx  = blockIdx.x;
    const int xcd = bx & 7;
    const int pb  = ((xcd >> 2) << 8) + (bx >> 3)*4 + (xcd & 3);  // bijective: batch b -> 4 XCDs
    const int b   = pb >> 8;
    const int p0  = (pb & 255) * 16;

    const int t    = threadIdx.x;
    const int w    = t >> 6;
    const int lane = t & 63;
    const float* xb = xyzp + (size_t)b*NP*4;

    for (int q = t; q < NP; q += 256) {
        const float4 v = *(const float4*)(xb + (size_t)q*4);
        xy[q*2 + 0] = v.x;
        xy[q*2 + 1] = v.y;
    }
    __syncthreads();

    // ---- mask build (contract off to match numpy d2 exactly) ----
    const int pl0 = p0 + w*4;
    unsigned long long wacc[4] = {0ULL, 0ULL, 0ULL, 0ULL};
    {
#pragma clang fp contract(off)
        float xi[4], yi[4];
        #pragma unroll
        for (int p = 0; p < 4; ++p) { xi[p] = xy[(pl0+p)*2]; yi[p] = xy[(pl0+p)*2+1]; }
        for (int c = 0; c < NP/64; ++c) {
            const float2 q = *(const float2*)(xy + (size_t)(c*64 + lane)*2);
            const bool keep = (lane == c);
            #pragma unroll
            for (int p = 0; p < 4; ++p) {
                const float dx = xi[p] - q.x;
                const float dy = yi[p] - q.y;
                const float dx2 = dx*dx;
                const float dy2 = dy*dy;
                const unsigned long long m = __ballot((dx2 + dy2) < R2);
                if (keep) wacc[p] = m;        // lane l keeps word l (j in [64l, 64l+64))
            }
        }
    }

    // ---- extraction: 32 smallest hit indices per point ----
    #pragma unroll
    for (int p = 0; p < 4; ++p) {
        unsigned long long wd = wacc[p];
        const int cnt = __popcll(wd);
        int pre = cnt;
        #pragma unroll
        for (int off = 1; off < 64; off <<= 1) {
            const int tv = __shfl_up(pre, off);
            if (lane >= off) pre += tv;
        }
        const int total = __shfl(pre, 63);
        int slot = pre - cnt;                 // exclusive prefix
        unsigned long long ww = wd;
        while (ww != 0ULL && slot < KNN) {
            const int bpos = __builtin_ctzll(ww);
            idxrow[(w*4 + p)*KNN + slot] = lane*64 + bpos;
            ww &= ww - 1ULL;
            ++slot;
        }
        const int iself = pl0 + p;
        for (int kk = min(total, KNN) + lane; kk < KNN; kk += 64)
            idxrow[(w*4 + p)*KNN + kk] = iself;
    }

    // ---- per-lane channel constants ----
    const int half = lane >> 5;
    const int lq   = lane & 31;
    const int c0   = lq * 4;
    float4 w2r[7];
    #pragma unroll
    for (int r = 0; r < 7; ++r)
        w2r[r] = *(const float4*)(Wm + (size_t)(256 + r)*DIMC + c0);
    const float4 bb4 = *(const float4*)(bbias + c0);

    float s1x=0.f,s1y=0.f,s1z=0.f,s1w=0.f;
    float s2x=0.f,s2y=0.f,s2z=0.f,s2w=0.f;
    float sxacc = 0.f, syacc = 0.f;
    const float* gbb = g + (size_t)b*NP*DIMC + c0;

    for (int rp = 0; rp < 2; ++rp) {
        // geo phase: lane handles pair (row = w*4+rp*2+half, k = lq)
        const int rloc = w*4 + rp*2 + half;
        const int ptl  = p0 + rloc;
        const int j0   = idxrow[rloc*KNN + lq];
        const float4 pj = *(const float4*)(xb + (size_t)j0*4);
        const float4 pi = *(const float4*)(xb + (size_t)ptl*4);
        const float dx = pi.x - pj.x;
        const float dy = pi.y - pj.y;
        const float dz = pi.z - pj.z;
        const float dwv = pi.w - pj.w;
        const float ts  = (dz == 0.f) ? 1e-6f : dz;
        const float rts = __builtin_amdgcn_rcpf(ts);
        const float sxv = dx*rts*640.f;
        const float syv = dy*rts*480.f;
        *(float4*)&geo[w][half][lq][0] = make_float4(dx, dy, dz, dwv);
        *(float4*)&geo[w][half][lq][4] = make_float4(sxv, syv, fabsf(dwv), __int_as_float(j0));
        sxacc += sxv; syacc += syv;
        __builtin_amdgcn_wave_barrier();

        // h phase: this lane's row is the SAME row it just built geo for
        const size_t rowg = (size_t)b*NP + ptl;
        const float4 ee = *(const float4*)(e + rowg*DIMC + c0);
        const float ecx = ee.x + bb4.x, ecy = ee.y + bb4.y;
        const float ecz = ee.z + bb4.z, ecw = ee.w + bb4.w;
        float mxx=-INFINITY,mxy=-INFINITY,mxz=-INFINITY,mxw=-INFINITY;
        float mnx= INFINITY,mny= INFINITY,mnz= INFINITY,mnw= INFINITY;
        #pragma unroll 4
        for (int k = 0; k < KNN; ++k) {
            const float4 g0 = *(const float4*)&geo[w][half][k][0];
            const float4 g1 = *(const float4*)&geo[w][half][k][4];
            const int jj = __float_as_int(g1.w);
            const float4 gg = *(const float4*)(gbb + (size_t)jj*DIMC);

            float h0 = ecx + gg.x;
            h0 = fmaf(g0.x, w2r[0].x, h0); h0 = fmaf(g0.y, w2r[1].x, h0);
            h0 = fmaf(g0.z, w2r[2].x, h0); h0 = fmaf(g0.w, w2r[3].x, h0);
            h0 = fmaf(g1.x, w2r[4].x, h0); h0 = fmaf(g1.y, w2r[5].x, h0);
            h0 = fmaf(g1.z, w2r[6].x, h0);
            mxx = fmaxf(mxx, h0); mnx = fminf(mnx, h0);
            s1x += h0; s2x = fmaf(h0, h0, s2x);

            float h1 = ecy + gg.y;
            h1 = fmaf(g0.x, w2r[0].y, h1); h1 = fmaf(g0.y, w2r[1].y, h1);
            h1 = fmaf(g0.z, w2r[2].y, h1); h1 = fmaf(g0.w, w2r[3].y, h1);
            h1 = fmaf(g1.x, w2r[4].y, h1); h1 = fmaf(g1.y, w2r[5].y, h1);
            h1 = fmaf(g1.z, w2r[6].y, h1);
            mxy = fmaxf(mxy, h1); mny = fminf(mny, h1);
            s1y += h1; s2y = fmaf(h1, h1, s2y);

            float h2 = ecz + gg.z;
            h2 = fmaf(g0.x, w2r[0].z, h2); h2 = fmaf(g0.y, w2r[1].z, h2);
            h2 = fmaf(g0.z, w2r[2].z, h2); h2 = fmaf(g0.w, w2r[3].z, h2);
            h2 = fmaf(g1.x, w2r[4].z, h2); h2 = fmaf(g1.y, w2r[5].z, h2);
            h2 = fmaf(g1.z, w2r[6].z, h2);
            mxz = fmaxf(mxz, h2); mnz = fminf(mnz, h2);
            s1z += h2; s2z = fmaf(h2, h2, s2z);

            float h3 = ecw + gg.w;
            h3 = fmaf(g0.x, w2r[0].w, h3); h3 = fmaf(g0.y, w2r[1].w, h3);
            h3 = fmaf(g0.z, w2r[2].w, h3); h3 = fmaf(g0.w, w2r[3].w, h3);
            h3 = fmaf(g1.x, w2r[4].w, h3); h3 = fmaf(g1.y, w2r[5].w, h3);
            h3 = fmaf(g1.z, w2r[6].w, h3);
            mxw = fmaxf(mxw, h3); mnw = fminf(mnw, h3);
            s1w += h3; s2w = fmaf(h3, h3, s2w);
        }
        *(float4*)(hmaxA + rowg*DIMC + c0) = make_float4(mxx, mxy, mxz, mxw);
        *(float4*)(hminA + rowg*DIMC + c0) = make_float4(mnx, mny, mnz, mnw);
        __builtin_amdgcn_wave_barrier();   // geo reused (overwritten) next rp
    }

    // ---- speed wave-reduce -> per-block double partial ----
    #pragma unroll
    for (int off = 32; off > 0; off >>= 1) {
        sxacc += __shfl_down(sxacc, off);
        syacc += __shfl_down(syacc, off);
    }
    if (lane == 0) { swr[w*2] = sxacc; swr[w*2+1] = syacc; }

    // ---- stat partials ----
    *(float4*)&l1s[w*2 + half][c0] = make_float4(s1x, s1y, s1z, s1w);
    *(float4*)&l2s[w*2 + half][c0] = make_float4(s2x, s2y, s2z, s2w);
    __syncthreads();
    if (t < DIMC) {
        float v = 0.f;
        #pragma unroll
        for (int r = 0; r < 8; ++r) v += l1s[r][t];
        stpartT[(size_t)t*MAINBLOCKS + pb] = v;
    } else {
        const int c = t - DIMC;
        float v = 0.f;
        #pragma unroll
        for (int r = 0; r < 8; ++r) v += l2s[r][c];
        stpartT[(size_t)(DIMC + c)*MAINBLOCKS + pb] = v;
    }
    if (t == 0) {
        const double s0 = ((double)swr[0] + (double)swr[2]) + ((double)swr[4] + (double)swr[6]);
        const double s1 = ((double)swr[1] + (double)swr[3]) + ((double)swr[5] + (double)swr[7]);
        spart[(size_t)pb*2 + 0] = s0;
        spart[(size_t)pb*2 + 1] = s1;
    }
}

// ---------------- kE: stat + mean-speed reduce, per-batch affine coefficients ----------------
__global__ __launch_bounds__(256) void kE(const float* __restrict__ stpartT,
                                          const double* __restrict__ spart,
                                          const float* __restrict__ Wm,
                                          const float* __restrict__ gamma,
                                          const float* __restrict__ beta,
                                          float* __restrict__ abuf,
                                          float* __restrict__ dbuf2)
{
    __shared__ double red[256][8];   // 16 KB
    const int c = blockIdx.x;        // 0..127
    const int t = threadIdx.x;

    red[t][0] = spart[(size_t)t*2];            // sx batch0
    red[t][1] = spart[(size_t)t*2 + 1];        // sy batch0
    red[t][2] = spart[(size_t)(t+256)*2];      // sx batch1
    red[t][3] = spart[(size_t)(t+256)*2 + 1];  // sy batch1
    red[t][4] = (double)stpartT[(size_t)c*MAINBLOCKS + t];                    // S1 b0
    red[t][5] = (double)stpartT[(size_t)c*MAINBLOCKS + 256 + t];              // S1 b1
    red[t][6] = (double)stpartT[(size_t)(c + DIMC)*MAINBLOCKS + t];           // S2 b0
    red[t][7] = (double)stpartT[(size_t)(c + DIMC)*MAINBLOCKS + 256 + t];     // S2 b1
    __syncthreads();
    for (int st = 128; st > 0; st >>= 1) {
        if (t < st) {
            #pragma unroll
            for (int q = 0; q < 8; ++q) red[t][q] += red[t+st][q];
        }
        __syncthreads();
    }
    if (t == 0) {
        const double NKd = (double)(NP*KNN);
        const float ms0x = (float)(red[0][0] / NKd);
        const float ms0y = (float)(red[0][1] / NKd);
        const float ms1x = (float)(red[0][2] / NKd);
        const float ms1y = (float)(red[0][3] / NKd);
        const float wx = Wm[263*DIMC + c];
        const float wy = Wm[264*DIMC + c];
        const double cb0 = (double)fmaf(ms0x, wx, ms0y*wy);
        const double cb1 = (double)fmaf(ms1x, wx, ms1y*wy);
        const double s1b0 = red[0][4], s1b1 = red[0][5];
        const double s2b0 = red[0][6], s2b1 = red[0][7];
        const double M  = (double)MTOT;
        const double S1 = s1b0 + s1b1 + NKd*(cb0 + cb1);
        const double S2 = (s2b0 + 2.0*cb0*s1b0 + NKd*cb0*cb0)
                        + (s2b1 + 2.0*cb1*s1b1 + NKd*cb1*cb1);
        const double mu  = S1 / M;
        const double var = S2 / M - mu*mu;
        const double inv = 1.0 / sqrt(var + 1e-5);
        const double a  = (double)gamma[c] * inv;
        const double db = (double)beta[c] - mu*a;
        abuf[c] = (float)a;
        dbuf2[c]        = (float)(db + cb0*a);
        dbuf2[DIMC + c] = (float)(db + cb1*a);
    }
}

// ---------------- kF: normalize + relu on the pre-reduced K-extremes ----------------
__global__ __launch_bounds__(256) void kF(const float* __restrict__ hmaxA,
                                          const float* __restrict__ hminA,
                                          const float* __restrict__ abuf,
                                          const float* __restrict__ dbuf2,
                                          float* __restrict__ out)
{
    const int gid = blockIdx.x*256 + threadIdx.x;
    const int row = gid >> 6;
    const int c0  = (gid & 63)*2;
    const int b   = row >> 12;
    const size_t off = (size_t)row*DIMC + c0;
    const float2 mx = *(const float2*)(hmaxA + off);
    const float2 mn = *(const float2*)(hminA + off);
    const float a0 = abuf[c0],  a1 = abuf[c0+1];
    const float d0 = dbuf2[b*DIMC + c0], d1 = dbuf2[b*DIMC + c0 + 1];
    const float h0 = (a0 >= 0.f) ? mx.x : mn.x;
    const float h1 = (a1 >= 0.f) ? mx.y : mn.y;
    float2 o;
    o.x = fmaxf(fmaf(h0, a0, d0), 0.0f);
    o.y = fmaxf(fmaf(h1, a1, d1), 0.0f);
    *(float2*)(out + off) = o;
}

extern "C" void kernel_launch(void* const* d_in, const int* in_sizes, int n_in,
                              void* d_out, int out_size, void* d_ws, size_t ws_size,
                              hipStream_t stream)
{
    const float* xyzp  = (const float*)d_in[0];
    const float* feat  = (const float*)d_in[1];
    const float* Wm    = (const float*)d_in[2];
    const float* bbias = (const float*)d_in[3];
    const float* gamma = (const float*)d_in[4];
    const float* beta  = (const float*)d_in[5];

    char* ws = (char*)d_ws;
    const size_t MB = 1u << 20;
    float*  g       = (float*) (ws + 1*MB);          // 4 MB
    float*  e       = (float*) (ws + 5*MB);          // 4 MB
    float*  hmaxA   = (float*) (ws + 9*MB);          // 4 MB
    float*  hminA   = (float*) (ws + 13*MB);         // 4 MB
    double* spart   = (double*)(ws + 17*MB);         // 8 KB (512 x double2)
    float*  abuf    = (float*) (ws + 17*MB + 65536); // 512 B
    float*  dbuf2   = (float*) (ws + 17*MB + 66560); // 1 KB
    float*  stpartT = (float*) (ws + 18*MB);         // 512 KB (256 x 512)

    k1 <<<256, 256, 0, stream>>>(feat, Wm, e, g);
    k2 <<<K2BLOCKS, 256, 0, stream>>>(xyzp, e, g, Wm, bbias, spart, hmaxA, hminA, stpartT);
    kE <<<DIMC, 256, 0, stream>>>(stpartT, spart, Wm, gamma, beta, abuf, dbuf2);
    kF <<<(NROWS*64)/256, 256, 0, stream>>>(hmaxA, hminA, abuf, dbuf2, (float*)d_out);
}

// Round 6
// 51.984 us; speedup vs baseline: 1.2905x; 1.2106x over previous
//
#include <hip/hip_runtime.h>
#include <math.h>

#define NB   2
#define NP   4096
#define KNN  32
#define DIMC 128
#define NROWS (NB*NP)          // 8192
#define MTOT  (NB*NP*KNN)      // 262144
#define K2BLOCKS 512           // 16 points each (4 per wave)
#define MAINBLOCKS 512

static constexpr float R2 = 0.04f;

// ---------------- k1: e = feat@W0, g = feat@W1 ----------------
// grid 256 = 64 rowblk x 4 colblk; block = 128 rows x 64 cols, thread = 8x4.
// A-tile staged ONCE in LDS (67.6 KB, no barriers in K-loop); interleaved rows
// (tr+16i) -> wave's 4 tr values hit disjoint bank quads (conflict-free b128
// broadcast). B read from global (32 KB W col-slice, L1/L2-hot, 256B/instr).
__global__ __launch_bounds__(256) void k1(const float* __restrict__ feat,
                                          const float* __restrict__ Wm,
                                          float* __restrict__ e,
                                          float* __restrict__ g)
{
    __shared__ float sa[128*132];          // 67.6 KB, rows padded to 132
    const int t      = threadIdx.x;
    const int rowblk = blockIdx.x >> 2;
    const int colblk = blockIdx.x & 3;
    const int cb     = colblk >> 1;        // 0 -> e, 1 -> g
    const int coff   = (colblk & 1) * 64;
    const int row0   = rowblk * 128;
    const int tr     = t >> 4;             // 0..15
    const int tc     = t & 15;             // 0..15
    const float* wsrc = Wm + (size_t)cb*128*DIMC + coff;

    // stage A tile (coalesced float4 global -> LDS)
    #pragma unroll
    for (int q = 0; q < 16; ++q) {
        const int fid = q*256 + t;         // 0..4095 float4 slots
        const int r   = fid >> 5;          // 0..127
        const int kq  = fid & 31;          // 0..31
        const float4 v = *(const float4*)(feat + (size_t)(row0 + r)*DIMC + kq*4);
        *(float4*)&sa[r*132 + kq*4] = v;
    }
    __syncthreads();

    float acc[8][4];
    #pragma unroll
    for (int i = 0; i < 8; ++i) { acc[i][0]=0.f; acc[i][1]=0.f; acc[i][2]=0.f; acc[i][3]=0.f; }

    #pragma unroll 2
    for (int k4 = 0; k4 < 32; ++k4) {
        float4 bw[4];
        #pragma unroll
        for (int j = 0; j < 4; ++j)
            bw[j] = *(const float4*)(wsrc + (size_t)(k4*4 + j)*DIMC + tc*4);
        float4 ar[8];
        #pragma unroll
        for (int i = 0; i < 8; ++i)
            ar[i] = *(const float4*)&sa[(tr + 16*i)*132 + k4*4];
        #pragma unroll
        for (int j = 0; j < 4; ++j) {
            #pragma unroll
            for (int i = 0; i < 8; ++i) {
                const float a = (j==0)?ar[i].x:(j==1)?ar[i].y:(j==2)?ar[i].z:ar[i].w;
                acc[i][0] = fmaf(a, bw[j].x, acc[i][0]);
                acc[i][1] = fmaf(a, bw[j].y, acc[i][1]);
                acc[i][2] = fmaf(a, bw[j].z, acc[i][2]);
                acc[i][3] = fmaf(a, bw[j].w, acc[i][3]);
            }
        }
    }

    float* dst = cb ? g : e;
    #pragma unroll
    for (int i = 0; i < 8; ++i)
        *(float4*)(dst + (size_t)(row0 + tr + 16*i)*DIMC + coff + tc*4) =
            make_float4(acc[i][0], acc[i][1], acc[i][2], acc[i][3]);
}

// ---------------- k2: mask + extract + geo + h (min/max over K) + stat partials ----------------
__global__ __launch_bounds__(256) void k2(const float* __restrict__ xyzp,
                                          const float* __restrict__ e,
                                          const float* __restrict__ g,
                                          const float* __restrict__ Wm,
                                          const float* __restrict__ bbias,
                                          double* __restrict__ spart,
                                          float* __restrict__ hmaxA,
                                          float* __restrict__ hminA,
                                          float* __restrict__ stpartT)
{
    __shared__ float xy[NP*2];                 // 32 KB
    __shared__ int   idxrow[16*KNN];           // 2 KB
    __shared__ float geo[4][2][KNN][8];        // 8 KB
    __shared__ float l1s[8][DIMC];             // 4 KB
    __shared__ float l2s[8][DIMC];             // 4 KB
    __shared__ float swr[8];

    const int bx  = blockIdx.x;
    const int xcd = bx & 7;
    const int pb  = ((xcd >> 2) << 8) + (bx >> 3)*4 + (xcd & 3);  // bijective: batch b -> 4 XCDs
    const int b   = pb >> 8;
    const int p0  = (pb & 255) * 16;

    const int t    = threadIdx.x;
    const int w    = t >> 6;
    const int lane = t & 63;
    const float* xb = xyzp + (size_t)b*NP*4;

    for (int q = t; q < NP; q += 256) {
        const float4 v = *(const float4*)(xb + (size_t)q*4);
        xy[q*2 + 0] = v.x;
        xy[q*2 + 1] = v.y;
    }
    __syncthreads();

    // ---- mask build (contract off to match numpy d2 exactly) ----
    const int pl0 = p0 + w*4;
    unsigned long long wacc[4] = {0ULL, 0ULL, 0ULL, 0ULL};
    {
#pragma clang fp contract(off)
        float xi[4], yi[4];
        #pragma unroll
        for (int p = 0; p < 4; ++p) { xi[p] = xy[(pl0+p)*2]; yi[p] = xy[(pl0+p)*2+1]; }
        for (int c = 0; c < NP/64; ++c) {
            const float2 q = *(const float2*)(xy + (size_t)(c*64 + lane)*2);
            const bool keep = (lane == c);
            #pragma unroll
            for (int p = 0; p < 4; ++p) {
                const float dx = xi[p] - q.x;
                const float dy = yi[p] - q.y;
                const float dx2 = dx*dx;
                const float dy2 = dy*dy;
                const unsigned long long m = __ballot((dx2 + dy2) < R2);
                if (keep) wacc[p] = m;        // lane l keeps word l (j in [64l, 64l+64))
            }
        }
    }

    // ---- extraction: 32 smallest hit indices per point ----
    #pragma unroll
    for (int p = 0; p < 4; ++p) {
        unsigned long long wd = wacc[p];
        const int cnt = __popcll(wd);
        int pre = cnt;
        #pragma unroll
        for (int off = 1; off < 64; off <<= 1) {
            const int tv = __shfl_up(pre, off);
            if (lane >= off) pre += tv;
        }
        const int total = __shfl(pre, 63);
        int slot = pre - cnt;                 // exclusive prefix
        unsigned long long ww = wd;
        while (ww != 0ULL && slot < KNN) {
            const int bpos = __builtin_ctzll(ww);
            idxrow[(w*4 + p)*KNN + slot] = lane*64 + bpos;
            ww &= ww - 1ULL;
            ++slot;
        }
        const int iself = pl0 + p;
        for (int kk = min(total, KNN) + lane; kk < KNN; kk += 64)
            idxrow[(w*4 + p)*KNN + kk] = iself;
    }

    // ---- per-lane channel constants ----
    const int half = lane >> 5;
    const int lq   = lane & 31;
    const int c0   = lq * 4;
    float4 w2r[7];
    #pragma unroll
    for (int r = 0; r < 7; ++r)
        w2r[r] = *(const float4*)(Wm + (size_t)(256 + r)*DIMC + c0);
    const float4 bb4 = *(const float4*)(bbias + c0);

    float s1x=0.f,s1y=0.f,s1z=0.f,s1w=0.f;
    float s2x=0.f,s2y=0.f,s2z=0.f,s2w=0.f;
    float sxacc = 0.f, syacc = 0.f;
    const float* gbb = g + (size_t)b*NP*DIMC + c0;

    for (int rp = 0; rp < 2; ++rp) {
        // geo phase: lane handles pair (row = w*4+rp*2+half, k = lq)
        const int rloc = w*4 + rp*2 + half;
        const int ptl  = p0 + rloc;
        const int j0   = idxrow[rloc*KNN + lq];
        const float4 pj = *(const float4*)(xb + (size_t)j0*4);
        const float4 pi = *(const float4*)(xb + (size_t)ptl*4);
        const float dx = pi.x - pj.x;
        const float dy = pi.y - pj.y;
        const float dz = pi.z - pj.z;
        const float dwv = pi.w - pj.w;
        const float ts  = (dz == 0.f) ? 1e-6f : dz;
        const float rts = __builtin_amdgcn_rcpf(ts);
        const float sxv = dx*rts*640.f;
        const float syv = dy*rts*480.f;
        *(float4*)&geo[w][half][lq][0] = make_float4(dx, dy, dz, dwv);
        *(float4*)&geo[w][half][lq][4] = make_float4(sxv, syv, fabsf(dwv), __int_as_float(j0));
        sxacc += sxv; syacc += syv;
        __builtin_amdgcn_wave_barrier();

        // h phase: this lane's row is the SAME row it just built geo for
        const size_t rowg = (size_t)b*NP + ptl;
        const float4 ee = *(const float4*)(e + rowg*DIMC + c0);
        const float ecx = ee.x + bb4.x, ecy = ee.y + bb4.y;
        const float ecz = ee.z + bb4.z, ecw = ee.w + bb4.w;
        float mxx=-INFINITY,mxy=-INFINITY,mxz=-INFINITY,mxw=-INFINITY;
        float mnx= INFINITY,mny= INFINITY,mnz= INFINITY,mnw= INFINITY;
        #pragma unroll 4
        for (int k = 0; k < KNN; ++k) {
            const float4 g0 = *(const float4*)&geo[w][half][k][0];
            const float4 g1 = *(const float4*)&geo[w][half][k][4];
            const int jj = __float_as_int(g1.w);
            const float4 gg = *(const float4*)(gbb + (size_t)jj*DIMC);

            float h0 = ecx + gg.x;
            h0 = fmaf(g0.x, w2r[0].x, h0); h0 = fmaf(g0.y, w2r[1].x, h0);
            h0 = fmaf(g0.z, w2r[2].x, h0); h0 = fmaf(g0.w, w2r[3].x, h0);
            h0 = fmaf(g1.x, w2r[4].x, h0); h0 = fmaf(g1.y, w2r[5].x, h0);
            h0 = fmaf(g1.z, w2r[6].x, h0);
            mxx = fmaxf(mxx, h0); mnx = fminf(mnx, h0);
            s1x += h0; s2x = fmaf(h0, h0, s2x);

            float h1 = ecy + gg.y;
            h1 = fmaf(g0.x, w2r[0].y, h1); h1 = fmaf(g0.y, w2r[1].y, h1);
            h1 = fmaf(g0.z, w2r[2].y, h1); h1 = fmaf(g0.w, w2r[3].y, h1);
            h1 = fmaf(g1.x, w2r[4].y, h1); h1 = fmaf(g1.y, w2r[5].y, h1);
            h1 = fmaf(g1.z, w2r[6].y, h1);
            mxy = fmaxf(mxy, h1); mny = fminf(mny, h1);
            s1y += h1; s2y = fmaf(h1, h1, s2y);

            float h2 = ecz + gg.z;
            h2 = fmaf(g0.x, w2r[0].z, h2); h2 = fmaf(g0.y, w2r[1].z, h2);
            h2 = fmaf(g0.z, w2r[2].z, h2); h2 = fmaf(g0.w, w2r[3].z, h2);
            h2 = fmaf(g1.x, w2r[4].z, h2); h2 = fmaf(g1.y, w2r[5].z, h2);
            h2 = fmaf(g1.z, w2r[6].z, h2);
            mxz = fmaxf(mxz, h2); mnz = fminf(mnz, h2);
            s1z += h2; s2z = fmaf(h2, h2, s2z);

            float h3 = ecw + gg.w;
            h3 = fmaf(g0.x, w2r[0].w, h3); h3 = fmaf(g0.y, w2r[1].w, h3);
            h3 = fmaf(g0.z, w2r[2].w, h3); h3 = fmaf(g0.w, w2r[3].w, h3);
            h3 = fmaf(g1.x, w2r[4].w, h3); h3 = fmaf(g1.y, w2r[5].w, h3);
            h3 = fmaf(g1.z, w2r[6].w, h3);
            mxw = fmaxf(mxw, h3); mnw = fminf(mnw, h3);
            s1w += h3; s2w = fmaf(h3, h3, s2w);
        }
        *(float4*)(hmaxA + rowg*DIMC + c0) = make_float4(mxx, mxy, mxz, mxw);
        *(float4*)(hminA + rowg*DIMC + c0) = make_float4(mnx, mny, mnz, mnw);
        __builtin_amdgcn_wave_barrier();   // geo reused (overwritten) next rp
    }

    // ---- speed wave-reduce -> per-block double partial ----
    #pragma unroll
    for (int off = 32; off > 0; off >>= 1) {
        sxacc += __shfl_down(sxacc, off);
        syacc += __shfl_down(syacc, off);
    }
    if (lane == 0) { swr[w*2] = sxacc; swr[w*2+1] = syacc; }

    // ---- stat partials ----
    *(float4*)&l1s[w*2 + half][c0] = make_float4(s1x, s1y, s1z, s1w);
    *(float4*)&l2s[w*2 + half][c0] = make_float4(s2x, s2y, s2z, s2w);
    __syncthreads();
    if (t < DIMC) {
        float v = 0.f;
        #pragma unroll
        for (int r = 0; r < 8; ++r) v += l1s[r][t];
        stpartT[(size_t)t*MAINBLOCKS + pb] = v;
    } else {
        const int c = t - DIMC;
        float v = 0.f;
        #pragma unroll
        for (int r = 0; r < 8; ++r) v += l2s[r][c];
        stpartT[(size_t)(DIMC + c)*MAINBLOCKS + pb] = v;
    }
    if (t == 0) {
        const double s0 = ((double)swr[0] + (double)swr[2]) + ((double)swr[4] + (double)swr[6]);
        const double s1 = ((double)swr[1] + (double)swr[3]) + ((double)swr[5] + (double)swr[7]);
        spart[(size_t)pb*2 + 0] = s0;
        spart[(size_t)pb*2 + 1] = s1;
    }
}

// ---------------- kE: stat + mean-speed reduce, per-batch affine coefficients ----------------
__global__ __launch_bounds__(256) void kE(const float* __restrict__ stpartT,
                                          const double* __restrict__ spart,
                                          const float* __restrict__ Wm,
                                          const float* __restrict__ gamma,
                                          const float* __restrict__ beta,
                                          float* __restrict__ abuf,
                                          float* __restrict__ dbuf2)
{
    __shared__ double red[256][8];   // 16 KB
    const int c = blockIdx.x;        // 0..127
    const int t = threadIdx.x;

    red[t][0] = spart[(size_t)t*2];            // sx batch0
    red[t][1] = spart[(size_t)t*2 + 1];        // sy batch0
    red[t][2] = spart[(size_t)(t+256)*2];      // sx batch1
    red[t][3] = spart[(size_t)(t+256)*2 + 1];  // sy batch1
    red[t][4] = (double)stpartT[(size_t)c*MAINBLOCKS + t];                    // S1 b0
    red[t][5] = (double)stpartT[(size_t)c*MAINBLOCKS + 256 + t];              // S1 b1
    red[t][6] = (double)stpartT[(size_t)(c + DIMC)*MAINBLOCKS + t];           // S2 b0
    red[t][7] = (double)stpartT[(size_t)(c + DIMC)*MAINBLOCKS + 256 + t];     // S2 b1
    __syncthreads();
    for (int st = 128; st > 0; st >>= 1) {
        if (t < st) {
            #pragma unroll
            for (int q = 0; q < 8; ++q) red[t][q] += red[t+st][q];
        }
        __syncthreads();
    }
    if (t == 0) {
        const double NKd = (double)(NP*KNN);
        const float ms0x = (float)(red[0][0] / NKd);
        const float ms0y = (float)(red[0][1] / NKd);
        const float ms1x = (float)(red[0][2] / NKd);
        const float ms1y = (float)(red[0][3] / NKd);
        const float wx = Wm[263*DIMC + c];
        const float wy = Wm[264*DIMC + c];
        const double cb0 = (double)fmaf(ms0x, wx, ms0y*wy);
        const double cb1 = (double)fmaf(ms1x, wx, ms1y*wy);
        const double s1b0 = red[0][4], s1b1 = red[0][5];
        const double s2b0 = red[0][6], s2b1 = red[0][7];
        const double M  = (double)MTOT;
        const double S1 = s1b0 + s1b1 + NKd*(cb0 + cb1);
        const double S2 = (s2b0 + 2.0*cb0*s1b0 + NKd*cb0*cb0)
                        + (s2b1 + 2.0*cb1*s1b1 + NKd*cb1*cb1);
        const double mu  = S1 / M;
        const double var = S2 / M - mu*mu;
        const double inv = 1.0 / sqrt(var + 1e-5);
        const double a  = (double)gamma[c] * inv;
        const double db = (double)beta[c] - mu*a;
        abuf[c] = (float)a;
        dbuf2[c]        = (float)(db + cb0*a);
        dbuf2[DIMC + c] = (float)(db + cb1*a);
    }
}

// ---------------- kF: normalize + relu on the pre-reduced K-extremes ----------------
__global__ __launch_bounds__(256) void kF(const float* __restrict__ hmaxA,
                                          const float* __restrict__ hminA,
                                          const float* __restrict__ abuf,
                                          const float* __restrict__ dbuf2,
                                          float* __restrict__ out)
{
    const int gid = blockIdx.x*256 + threadIdx.x;
    const int row = gid >> 6;
    const int c0  = (gid & 63)*2;
    const int b   = row >> 12;
    const size_t off = (size_t)row*DIMC + c0;
    const float2 mx = *(const float2*)(hmaxA + off);
    const float2 mn = *(const float2*)(hminA + off);
    const float a0 = abuf[c0],  a1 = abuf[c0+1];
    const float d0 = dbuf2[b*DIMC + c0], d1 = dbuf2[b*DIMC + c0 + 1];
    const float h0 = (a0 >= 0.f) ? mx.x : mn.x;
    const float h1 = (a1 >= 0.f) ? mx.y : mn.y;
    float2 o;
    o.x = fmaxf(fmaf(h0, a0, d0), 0.0f);
    o.y = fmaxf(fmaf(h1, a1, d1), 0.0f);
    *(float2*)(out + off) = o;
}

extern "C" void kernel_launch(void* const* d_in, const int* in_sizes, int n_in,
                              void* d_out, int out_size, void* d_ws, size_t ws_size,
                              hipStream_t stream)
{
    const float* xyzp  = (const float*)d_in[0];
    const float* feat  = (const float*)d_in[1];
    const float* Wm    = (const float*)d_in[2];
    const float* bbias = (const float*)d_in[3];
    const float* gamma = (const float*)d_in[4];
    const float* beta  = (const float*)d_in[5];

    char* ws = (char*)d_ws;
    const size_t MB = 1u << 20;
    float*  g       = (float*) (ws + 1*MB);          // 4 MB
    float*  e       = (float*) (ws + 5*MB);          // 4 MB
    float*  hmaxA   = (float*) (ws + 9*MB);          // 4 MB
    float*  hminA   = (float*) (ws + 13*MB);         // 4 MB
    double* spart   = (double*)(ws + 17*MB);         // 8 KB (512 x double2)
    float*  abuf    = (float*) (ws + 17*MB + 65536); // 512 B
    float*  dbuf2   = (float*) (ws + 17*MB + 66560); // 1 KB
    float*  stpartT = (float*) (ws + 18*MB);         // 512 KB (256 x 512)

    k1 <<<256, 256, 0, stream>>>(feat, Wm, e, g);
    k2 <<<K2BLOCKS, 256, 0, stream>>>(xyzp, e, g, Wm, bbias, spart, hmaxA, hminA, stpartT);
    kE <<<DIMC, 256, 0, stream>>>(stpartT, spart, Wm, gamma, beta, abuf, dbuf2);
    kF <<<(NROWS*64)/256, 256, 0, stream>>>(hmaxA, hminA, abuf, dbuf2, (float*)d_out);
}